// Round 6
// baseline (703.865 us; speedup 1.0000x reference)
//
#include <hip/hip_runtime.h>
#include <math.h>

// Problem constants (from reference)
#define NN 50000
#define EE 800000
#define NB ((NN + 255) / 256)   // scan blocks

typedef short v8s __attribute__((ext_vector_type(8)));
typedef float v4f __attribute__((ext_vector_type(4)));

__device__ __forceinline__ ushort f2bf(float f) {
    uint u = __float_as_uint(f);
    uint r = (u + 0x7fffu + ((u >> 16) & 1u)) >> 16;
    return (ushort)r;
}
__device__ __forceinline__ float bf2f(ushort h) {
    return __uint_as_float(((uint)h) << 16);
}
// leaky_relu(x,0.2) = 0.6x + 0.4|x|
__device__ __forceinline__ float lrelu(float x) {
    return fmaf(0.4f, fabsf(x), 0.6f * x);
}

// DPP partial reductions (no LDS pipe).
template <int CTRL>
__device__ __forceinline__ float dppadd(float x) {
    int y = __builtin_amdgcn_update_dpp(0, __float_as_int(x), CTRL, 0xf, 0xf, true);
    return x + __int_as_float(y);
}
__device__ __forceinline__ float sum8(float x) {   // all-lane sum within 8-groups
    x = dppadd<0xB1>(x);    // quad_perm xor1
    x = dppadd<0x4E>(x);    // quad_perm xor2
    x = dppadd<0x141>(x);   // row_half_mirror
    return x;
}
__device__ __forceinline__ float sum16(float x) {  // all-lane sum within 16-rows
    x = sum8(x);
    x = dppadd<0x140>(x);   // row_mirror
    return x;
}
__device__ __forceinline__ float expclamp(float t) {
    return __expf(fminf(fmaxf(t, -60.f), 80.f));
}

// ---------------------------------------------------------------------------
// CSR build: histogram -> 3-phase parallel scan -> scatter
// ---------------------------------------------------------------------------
__global__ __launch_bounds__(256) void k_hist(const int* __restrict__ dst, int* __restrict__ deg) {
    int e = blockIdx.x * 256 + threadIdx.x;
    if (e < EE) atomicAdd(&deg[dst[e]], 1);
}

__global__ __launch_bounds__(256) void k_scan1(const int* __restrict__ deg, int* __restrict__ bsum) {
    __shared__ int sm[4];
    int t = threadIdx.x;
    int idx = blockIdx.x * 256 + t;
    int x = (idx < NN) ? deg[idx] : 0;
    #pragma unroll
    for (int o = 1; o < 64; o <<= 1) x += __shfl_xor(x, o);
    if ((t & 63) == 0) sm[t >> 6] = x;
    __syncthreads();
    if (t == 0) bsum[blockIdx.x] = sm[0] + sm[1] + sm[2] + sm[3];
}

// single-block 256-wide scan: out = exclusive prefix of in[0..n)
__global__ __launch_bounds__(256) void k_scan256(const int* __restrict__ in,
                                                 int* __restrict__ out, int n) {
    __shared__ int sm[256];
    int t = threadIdx.x;
    int v = (t < n) ? in[t] : 0;
    sm[t] = v;
    __syncthreads();
    for (int o = 1; o < 256; o <<= 1) {
        int a = (t >= o) ? sm[t - o] : 0;
        __syncthreads();
        sm[t] += a;
        __syncthreads();
    }
    if (t < n) out[t] = sm[t] - v;   // exclusive
}

__global__ __launch_bounds__(256) void k_scan3(const int* __restrict__ deg,
                                               const int* __restrict__ boff,
                                               int* __restrict__ rowptr,
                                               int* __restrict__ cursor) {
    __shared__ int sm[256];
    int t = threadIdx.x;
    int idx = blockIdx.x * 256 + t;
    int v = (idx < NN) ? deg[idx] : 0;
    sm[t] = v;
    __syncthreads();
    for (int o = 1; o < 256; o <<= 1) {
        int a = (t >= o) ? sm[t - o] : 0;
        __syncthreads();
        sm[t] += a;
        __syncthreads();
    }
    int incl = sm[t] + boff[blockIdx.x];
    if (idx < NN) { rowptr[idx + 1] = incl; cursor[idx] = incl - v; }
    if (idx == 0) rowptr[0] = 0;
}

__global__ __launch_bounds__(256) void k_scatter(const int* __restrict__ src,
                                                 const int* __restrict__ dst,
                                                 int* __restrict__ cursor,
                                                 int* __restrict__ csrc) {
    int e = blockIdx.x * 256 + threadIdx.x;
    if (e < EE) {
        int d = dst[e];
        int pos = atomicAdd(&cursor[d], 1);
        csrc[pos] = src[e];
    }
}

// --- degree-sorted node permutation (counting sort over 256 buckets) ---
__global__ __launch_bounds__(256) void k_dcount(const int* __restrict__ deg, int* __restrict__ dcnt) {
    int n = blockIdx.x * 256 + threadIdx.x;
    if (n < NN) atomicAdd(&dcnt[min(deg[n], 255)], 1);
}
__global__ __launch_bounds__(256) void k_dplace(const int* __restrict__ deg,
                                                int* __restrict__ doff,
                                                int* __restrict__ perm) {
    int n = blockIdx.x * 256 + threadIdx.x;
    if (n < NN) {
        int pos = atomicAdd(&doff[min(deg[n], 255)], 1);
        perm[pos] = n;
    }
}

// ---------------------------------------------------------------------------
// Weight conversion: W [128 x FOUT] fp32 -> bf16 hi/lo in MFMA-fragment order:
// element (col = t*16+m, k = c*32+quad*8+j) at (((t*4+c)*4+quad)*16+m)*8+j.
// ---------------------------------------------------------------------------
struct WPack {
    const float* W[8];
    ushort* Th[8];
    ushort* Tl[8];
    int fout[8];
};

__global__ __launch_bounds__(256) void k_conv_w(WPack p) {
    int wi = blockIdx.y;
    int fout = p.fout[wi];
    int total = 128 * fout;
    int i = blockIdx.x * 256 + threadIdx.x;
    if (i >= total) return;
    int k = i / fout;
    int n = i - k * fout;
    float f = p.W[wi][i];
    ushort h = f2bf(f);
    float lo = f - bf2f(h);
    int t = n >> 4, m = n & 15, c = k >> 5, quad = (k >> 3) & 3, j = k & 7;
    int flat = ((((t * 4 + c) * 4 + quad) * 16 + m) << 3) + j;
    p.Th[wi][flat] = h;
    p.Tl[wi][flat] = f2bf(lo);
}

// ---------------------------------------------------------------------------
// Split-bf16 MFMA GEMM with LDS-staged B: O_w = X @ W_w (+ B_w), K=128.
// 4 waves/block, each wave computes a 32-row (2x16 strip) x FOUT slab.
// Per w: the whole fragment-packed weight matrix (hi+lo, <=64 KB) is staged
// into LDS cooperatively, then fragments come from ds_read_b128 (~120 cyc)
// instead of L2 (~250 cyc) -> K-loop is MFMA-bound, not load-latency-bound.
// CVT=true: A read from fp32 X and split to bf16 hi/lo on the fly (layer 0).
// ---------------------------------------------------------------------------
template <int FOUT, int NW, bool CVT>
__global__ __launch_bounds__(256) void k_gemm_mfma(
    const float* __restrict__ Xf,
    const ushort* __restrict__ Xh, const ushort* __restrict__ Xl,
    const ushort* __restrict__ T0h, const ushort* __restrict__ T0l, const float* __restrict__ B0,
    const ushort* __restrict__ T1h, const ushort* __restrict__ T1l, const float* __restrict__ B1,
    const ushort* __restrict__ T2h, const ushort* __restrict__ T2l,
    float* __restrict__ O0, float* __restrict__ O1, float* __restrict__ O2)
{
    __shared__ ushort Bsh[128 * FOUT];   // 32 KB (FOUT=128)
    __shared__ ushort Bsl[128 * FOUT];

    const int lane = threadIdx.x & 63;
    const int wid  = threadIdx.x >> 6;
    const int m    = lane & 15;
    const int quad = lane >> 4;
    const int row0 = blockIdx.x * 128 + wid * 32;

    v8s ah[2][4], al[2][4];
    #pragma unroll
    for (int s = 0; s < 2; ++s) {
        int arow = row0 + s * 16 + m;
        if (arow > NN - 1) arow = NN - 1;
        #pragma unroll
        for (int c = 0; c < 4; ++c) {
            size_t off = (size_t)arow * 128 + c * 32 + quad * 8;
            if constexpr (CVT) {
                float4 f0 = *(const float4*)(Xf + off);
                float4 f1 = *(const float4*)(Xf + off + 4);
                const float fe[8] = {f0.x, f0.y, f0.z, f0.w, f1.x, f1.y, f1.z, f1.w};
                #pragma unroll
                for (int e = 0; e < 8; ++e) {
                    ushort h = f2bf(fe[e]);
                    float lo = fe[e] - bf2f(h);
                    ah[s][c][e] = (short)h;
                    al[s][c][e] = (short)(__float_as_uint(lo) >> 16);  // truncate lo
                }
            } else {
                ah[s][c] = *(const v8s*)(Xh + off);
                al[s][c] = *(const v8s*)(Xl + off);
            }
        }
    }

    const ushort* Th[3] = {T0h, T1h, T2h};
    const ushort* Tl[3] = {T0l, T1l, T2l};
    const float*  Bs[3] = {B0, B1, nullptr};
    float*        Os[3] = {O0, O1, O2};

    #pragma unroll
    for (int w = 0; w < NW; ++w) {
        const ushort* th = Th[w];
        const ushort* tl = Tl[w];
        // stage W_w (hi+lo) into LDS: 128*FOUT shorts each, 16B chunks
        if (w > 0) __syncthreads();   // previous tile's reads done
        constexpr int CHUNKS = (128 * FOUT) / 8;
        for (int idx = threadIdx.x; idx < CHUNKS; idx += 256) {
            ((uint4*)Bsh)[idx] = ((const uint4*)th)[idx];
            ((uint4*)Bsl)[idx] = ((const uint4*)tl)[idx];
        }
        __syncthreads();

        const float* bias = Bs[w];
        float* O = Os[w];
        #pragma unroll
        for (int t = 0; t < FOUT / 16; ++t) {
            v4f acc[2] = {{0.f,0.f,0.f,0.f},{0.f,0.f,0.f,0.f}};
            #pragma unroll
            for (int c = 0; c < 4; ++c) {
                int boff = t * 2048 + (c * 4 + quad) * 128 + m * 8;
                v8s bh = *(const v8s*)&Bsh[boff];
                v8s bl = *(const v8s*)&Bsl[boff];
                acc[0] = __builtin_amdgcn_mfma_f32_16x16x32_bf16(al[0][c], bh, acc[0], 0, 0, 0);
                acc[0] = __builtin_amdgcn_mfma_f32_16x16x32_bf16(ah[0][c], bl, acc[0], 0, 0, 0);
                acc[0] = __builtin_amdgcn_mfma_f32_16x16x32_bf16(ah[0][c], bh, acc[0], 0, 0, 0);
                acc[1] = __builtin_amdgcn_mfma_f32_16x16x32_bf16(al[1][c], bh, acc[1], 0, 0, 0);
                acc[1] = __builtin_amdgcn_mfma_f32_16x16x32_bf16(ah[1][c], bl, acc[1], 0, 0, 0);
                acc[1] = __builtin_amdgcn_mfma_f32_16x16x32_bf16(ah[1][c], bh, acc[1], 0, 0, 0);
            }
            const int col = t * 16 + m;
            float badd = bias ? bias[col] : 0.f;
            #pragma unroll
            for (int s = 0; s < 2; ++s) {
                #pragma unroll
                for (int j = 0; j < 4; ++j) {
                    int r = row0 + s * 16 + quad * 4 + j;
                    if (r < NN) O[(size_t)r * FOUT + col] = acc[s][j] + badd;
                }
            }
        }
    }
}

// ---------------------------------------------------------------------------
// Aggregation layers 0/1: one wave per (degree-sorted) node, 8 edges per
// main-loop iteration. Lane l: half = l>>5 selects edge of each pair; j = l&31
// owns channels 4j..4j+3. Head = j>>3 -> logit reduce = sum8 (3 DPP).
// 32-bit element indexing for gathers. Epilogue: +res +bias, ELU, bf16 hi/lo.
// ---------------------------------------------------------------------------
__global__ __launch_bounds__(256) void k_agg01(const float4* __restrict__ XL4,
                                               const float4* __restrict__ XR4,
                                               const float4* __restrict__ RES4,
                                               const float* __restrict__ att,
                                               const float* __restrict__ bias,
                                               const int* __restrict__ rowptr,
                                               const int* __restrict__ csrc,
                                               const int* __restrict__ perm,
                                               ushort* __restrict__ Hh,
                                               ushort* __restrict__ Hl) {
    const int lane = threadIdx.x & 63;
    const int wid = threadIdx.x >> 6;
    const int idx = blockIdx.x * 4 + wid;
    if (idx >= NN) return;
    const int n = perm[idx];
    const int beg = rowptr[n];
    const int end = rowptr[n + 1];
    const int half = lane >> 5;
    const uint j = lane & 31;

    const float4 xr = XR4[(uint)n * 32u + j];
    const float4 at = ((const float4*)att)[j];
    float4 s = {0.f, 0.f, 0.f, 0.f};
    float d = 0.f;
    const int e1 = end - 1;

    for (int i = beg; i < end; i += 8) {
        int i0 = i + half;
        int i1 = i + 2 + half;
        int i2 = i + 4 + half;
        int i3 = i + 6 + half;
        uint s0 = (uint)csrc[min(i0, e1)];
        uint s1 = (uint)csrc[min(i1, e1)];
        uint s2 = (uint)csrc[min(i2, e1)];
        uint s3 = (uint)csrc[min(i3, e1)];
        float4 v0 = XL4[s0 * 32u + j];
        float4 v1 = XL4[s1 * 32u + j];
        float4 v2 = XL4[s2 * 32u + j];
        float4 v3 = XL4[s3 * 32u + j];
        #pragma unroll
        for (int u = 0; u < 4; ++u) {
            float4 v = (u == 0) ? v0 : (u == 1) ? v1 : (u == 2) ? v2 : v3;
            int ii = (u == 0) ? i0 : (u == 1) ? i1 : (u == 2) ? i2 : i3;
            float t0 = lrelu(v.x + xr.x) * at.x;
            t0 = fmaf(lrelu(v.y + xr.y), at.y, t0);
            t0 = fmaf(lrelu(v.z + xr.z), at.z, t0);
            t0 = fmaf(lrelu(v.w + xr.w), at.w, t0);
            float p = expclamp(sum8(t0));
            if (ii >= end) p = 0.f;
            d += p;
            s.x = fmaf(p, v.x, s.x); s.y = fmaf(p, v.y, s.y);
            s.z = fmaf(p, v.z, s.z); s.w = fmaf(p, v.w, s.w);
        }
    }

    // combine the two edge-halves
    d   += __shfl_xor(d, 32);
    s.x += __shfl_xor(s.x, 32);
    s.y += __shfl_xor(s.y, 32);
    s.z += __shfl_xor(s.z, 32);
    s.w += __shfl_xor(s.w, 32);

    if (half == 0) {
        float inv = (d > 0.f) ? 1.f / d : 0.f;
        float4 rv = RES4[(uint)n * 32u + j];
        float4 bv = ((const float4*)bias)[j];
        float o0 = fmaf(s.x, inv, rv.x + bv.x);
        float o1 = fmaf(s.y, inv, rv.y + bv.y);
        float o2 = fmaf(s.z, inv, rv.z + bv.z);
        float o3 = fmaf(s.w, inv, rv.w + bv.w);
        o0 = o0 > 0.f ? o0 : __expf(o0) - 1.f;   // ELU
        o1 = o1 > 0.f ? o1 : __expf(o1) - 1.f;
        o2 = o2 > 0.f ? o2 : __expf(o2) - 1.f;
        o3 = o3 > 0.f ? o3 : __expf(o3) - 1.f;
        ushort4 h, l;
        h.x = f2bf(o0); l.x = f2bf(o0 - bf2f(h.x));
        h.y = f2bf(o1); l.y = f2bf(o1 - bf2f(h.y));
        h.z = f2bf(o2); l.z = f2bf(o2 - bf2f(h.z));
        h.w = f2bf(o3); l.w = f2bf(o3 - bf2f(h.w));
        *(ushort4*)(Hh + (uint)n * 128u + 4u * j) = h;
        *(ushort4*)(Hl + (uint)n * 128u + 4u * j) = l;
    }
}

// ---------------------------------------------------------------------------
// Aggregation layer 2: F=64, H=1, degree-sorted. 8 edges per iteration
// (2 masked quad-passes). Quarter q = l>>4 selects edge; jj = l&15 owns
// channels 4jj..4jj+3. reduce16 = 4 DPP.
// ---------------------------------------------------------------------------
__global__ __launch_bounds__(256) void k_agg2(const float4* __restrict__ XL4,
                                              const float4* __restrict__ XR4,
                                              const float* __restrict__ att,
                                              const float* __restrict__ bias,
                                              const int* __restrict__ rowptr,
                                              const int* __restrict__ csrc,
                                              const int* __restrict__ perm,
                                              float* __restrict__ OUT) {
    const int lane = threadIdx.x & 63;
    const int wid = threadIdx.x >> 6;
    const int idx = blockIdx.x * 4 + wid;
    if (idx >= NN) return;
    const int n = perm[idx];
    const int beg = rowptr[n];
    const int end = rowptr[n + 1];
    const int q = lane >> 4;
    const uint jj = lane & 15;

    const float4 xr = XR4[(uint)n * 16u + jj];
    const float4 at = ((const float4*)att)[jj];
    float4 s = {0.f, 0.f, 0.f, 0.f};
    float d = 0.f;
    const int e1 = end - 1;

    for (int i = beg; i < end; i += 8) {
        int i0 = i + q;
        int i1 = i + 4 + q;
        uint s0 = (uint)csrc[min(i0, e1)];
        uint s1 = (uint)csrc[min(i1, e1)];
        float4 v0 = XL4[s0 * 16u + jj];
        float4 v1 = XL4[s1 * 16u + jj];
        #pragma unroll
        for (int u = 0; u < 2; ++u) {
            float4 v = (u == 0) ? v0 : v1;
            int ii = (u == 0) ? i0 : i1;
            float t0 = lrelu(v.x + xr.x) * at.x;
            t0 = fmaf(lrelu(v.y + xr.y), at.y, t0);
            t0 = fmaf(lrelu(v.z + xr.z), at.z, t0);
            t0 = fmaf(lrelu(v.w + xr.w), at.w, t0);
            float p = expclamp(sum16(t0));
            if (ii >= end) p = 0.f;
            d += p;
            s.x = fmaf(p, v.x, s.x); s.y = fmaf(p, v.y, s.y);
            s.z = fmaf(p, v.z, s.z); s.w = fmaf(p, v.w, s.w);
        }
    }

    // combine the four quarters
    d   += __shfl_xor(d, 16);   d   += __shfl_xor(d, 32);
    s.x += __shfl_xor(s.x, 16); s.x += __shfl_xor(s.x, 32);
    s.y += __shfl_xor(s.y, 16); s.y += __shfl_xor(s.y, 32);
    s.z += __shfl_xor(s.z, 16); s.z += __shfl_xor(s.z, 32);
    s.w += __shfl_xor(s.w, 16); s.w += __shfl_xor(s.w, 32);

    if (lane < 16) {
        float inv = (d > 0.f) ? 1.f / d : 0.f;
        float4 bv = ((const float4*)bias)[jj];
        float4 o;
        o.x = fmaf(s.x, inv, bv.x);
        o.y = fmaf(s.y, inv, bv.y);
        o.z = fmaf(s.z, inv, bv.z);
        o.w = fmaf(s.w, inv, bv.w);
        *(float4*)(OUT + (uint)n * 64u + 4u * jj) = o;
    }
}

// ---------------------------------------------------------------------------
extern "C" void kernel_launch(void* const* d_in, const int* in_sizes, int n_in,
                              void* d_out, int out_size, void* d_ws, size_t ws_size,
                              hipStream_t stream) {
    const float* x    = (const float*)d_in[0];
    const int*   ei   = (const int*)d_in[1];
    const int*   esrc = ei;
    const int*   edst = ei + EE;

    const float* Wl0 = (const float*)d_in[2];
    const float* bl0 = (const float*)d_in[3];
    const float* Wr0 = (const float*)d_in[4];
    const float* br0 = (const float*)d_in[5];
    const float* at0 = (const float*)d_in[6];
    const float* b0  = (const float*)d_in[7];
    const float* rs0 = (const float*)d_in[8];
    const float* Wl1 = (const float*)d_in[9];
    const float* bl1 = (const float*)d_in[10];
    const float* Wr1 = (const float*)d_in[11];
    const float* br1 = (const float*)d_in[12];
    const float* at1 = (const float*)d_in[13];
    const float* b1  = (const float*)d_in[14];
    const float* rs1 = (const float*)d_in[15];
    const float* Wl2 = (const float*)d_in[16];
    const float* bl2 = (const float*)d_in[17];
    const float* Wr2 = (const float*)d_in[18];
    const float* br2 = (const float*)d_in[19];
    const float* at2 = (const float*)d_in[20];
    const float* b2  = (const float*)d_in[21];

    float* out = (float*)d_out;

    // --- workspace layout ---
    float* XL  = (float*)d_ws;                 // [NN*128] fp32 row-major
    float* XR  = XL + (size_t)NN * 128;
    float* RES = XR + (size_t)NN * 128;
    ushort* Xh = (ushort*)(RES + (size_t)NN * 128);   // [NN*128] bf16-hi (H)
    ushort* Xl_ = Xh + (size_t)NN * 128;              // [NN*128] bf16-lo (H)
    ushort* Wth = Xl_ + (size_t)NN * 128;
    const int wsz[8] = {16384, 16384, 16384, 16384, 16384, 16384, 8192, 8192};
    ushort* th[8]; ushort* tl[8];
    {
        ushort* p = Wth;
        for (int i = 0; i < 8; ++i) { th[i] = p; p += wsz[i]; }
        for (int i = 0; i < 8; ++i) { tl[i] = p; p += wsz[i]; }
    }
    int* deg    = (int*)(Wth + 2 * (6 * 16384 + 2 * 8192));
    int* dcnt   = deg + NN;                    // 256  (memset together with deg)
    int* rowptr = dcnt + 256;                  // NN+1
    int* cursor = rowptr + (NN + 1);
    int* csrc   = cursor + NN;                 // EE
    int* bsum   = csrc + EE;                   // NB
    int* boff   = bsum + NB;                   // NB
    int* doff   = boff + NB;                   // 256
    int* perm   = doff + 256;                  // NN

    // --- CSR build + degree sort (graph identical across layers) ---
    hipMemsetAsync(deg, 0, (NN + 256) * sizeof(int), stream);   // deg + dcnt
    k_hist<<<(EE + 255) / 256, 256, 0, stream>>>(edst, deg);
    k_scan1<<<NB, 256, 0, stream>>>(deg, bsum);
    k_scan256<<<1, 256, 0, stream>>>(bsum, boff, NB);
    k_scan3<<<NB, 256, 0, stream>>>(deg, boff, rowptr, cursor);
    k_scatter<<<(EE + 255) / 256, 256, 0, stream>>>(esrc, edst, cursor, csrc);
    k_dcount<<<(NN + 255) / 256, 256, 0, stream>>>(deg, dcnt);
    k_scan256<<<1, 256, 0, stream>>>(dcnt, doff, 256);
    k_dplace<<<(NN + 255) / 256, 256, 0, stream>>>(deg, doff, perm);

    // --- weight conversion ---
    WPack wp;
    const float* Ws[8] = {Wl0, Wr0, rs0, Wl1, Wr1, rs1, Wl2, Wr2};
    const int fouts[8] = {128, 128, 128, 128, 128, 128, 64, 64};
    for (int i = 0; i < 8; ++i) { wp.W[i] = Ws[i]; wp.Th[i] = th[i]; wp.Tl[i] = tl[i]; wp.fout[i] = fouts[i]; }
    k_conv_w<<<dim3(64, 8), 256, 0, stream>>>(wp);

    const int gemm_grid = (NN + 127) / 128;
    const int agg_grid  = (NN + 3) / 4;

    // --- Layer 0 (A from fp32 x, split on the fly) ---
    k_gemm_mfma<128, 3, true><<<gemm_grid, 256, 0, stream>>>(x, nullptr, nullptr,
        th[0], tl[0], bl0, th[1], tl[1], br0, th[2], tl[2], XL, XR, RES);
    k_agg01<<<agg_grid, 256, 0, stream>>>((const float4*)XL, (const float4*)XR, (const float4*)RES,
        at0, b0, rowptr, csrc, perm, Xh, Xl_);

    // --- Layer 1 ---
    k_gemm_mfma<128, 3, false><<<gemm_grid, 256, 0, stream>>>(nullptr, Xh, Xl_,
        th[3], tl[3], bl1, th[4], tl[4], br1, th[5], tl[5], XL, XR, RES);
    k_agg01<<<agg_grid, 256, 0, stream>>>((const float4*)XL, (const float4*)XR, (const float4*)RES,
        at1, b1, rowptr, csrc, perm, Xh, Xl_);

    // --- Layer 2 (heads=1, C=64, no residual, no ELU) ---
    k_gemm_mfma<64, 2, false><<<gemm_grid, 256, 0, stream>>>(nullptr, Xh, Xl_,
        th[6], tl[6], bl2, th[7], tl[7], br2, nullptr, nullptr, XL, XR, nullptr);
    k_agg2<<<agg_grid, 256, 0, stream>>>((const float4*)XL, (const float4*)XR, at2, b2, rowptr, csrc, perm, out);
}

// Round 7
// 459.045 us; speedup vs baseline: 1.5333x; 1.5333x over previous
//
#include <hip/hip_runtime.h>
#include <math.h>

// Problem constants (from reference)
#define NN 50000
#define EE 800000
#define NB ((NN + 255) / 256)   // scan blocks

typedef short v8s __attribute__((ext_vector_type(8)));
typedef float v4f __attribute__((ext_vector_type(4)));

__device__ __forceinline__ ushort f2bf(float f) {
    uint u = __float_as_uint(f);
    uint r = (u + 0x7fffu + ((u >> 16) & 1u)) >> 16;
    return (ushort)r;
}
__device__ __forceinline__ float bf2f(ushort h) {
    return __uint_as_float(((uint)h) << 16);
}
// leaky_relu(x,0.2) = 0.6x + 0.4|x|
__device__ __forceinline__ float lrelu(float x) {
    return fmaf(0.4f, fabsf(x), 0.6f * x);
}

// DPP partial reductions (no LDS pipe).
template <int CTRL>
__device__ __forceinline__ float dppadd(float x) {
    int y = __builtin_amdgcn_update_dpp(0, __float_as_int(x), CTRL, 0xf, 0xf, true);
    return x + __int_as_float(y);
}
__device__ __forceinline__ float sum8(float x) {   // all-lane sum within 8-groups
    x = dppadd<0xB1>(x);    // quad_perm xor1
    x = dppadd<0x4E>(x);    // quad_perm xor2
    x = dppadd<0x141>(x);   // row_half_mirror
    return x;
}
__device__ __forceinline__ float sum16(float x) {  // all-lane sum within 16-rows
    x = sum8(x);
    x = dppadd<0x140>(x);   // row_mirror
    return x;
}
__device__ __forceinline__ float expclamp(float t) {
    return __expf(fminf(fmaxf(t, -60.f), 80.f));
}

// ---------------------------------------------------------------------------
// CSR build: histogram -> 3-phase parallel scan -> scatter
// ---------------------------------------------------------------------------
__global__ __launch_bounds__(256) void k_hist(const int* __restrict__ dst, int* __restrict__ deg) {
    int e = blockIdx.x * 256 + threadIdx.x;
    if (e < EE) atomicAdd(&deg[dst[e]], 1);
}

__global__ __launch_bounds__(256) void k_scan1(const int* __restrict__ deg, int* __restrict__ bsum) {
    __shared__ int sm[4];
    int t = threadIdx.x;
    int idx = blockIdx.x * 256 + t;
    int x = (idx < NN) ? deg[idx] : 0;
    #pragma unroll
    for (int o = 1; o < 64; o <<= 1) x += __shfl_xor(x, o);
    if ((t & 63) == 0) sm[t >> 6] = x;
    __syncthreads();
    if (t == 0) bsum[blockIdx.x] = sm[0] + sm[1] + sm[2] + sm[3];
}

// single-block 256-wide scan: out = exclusive prefix of in[0..n)
__global__ __launch_bounds__(256) void k_scan256(const int* __restrict__ in,
                                                 int* __restrict__ out, int n) {
    __shared__ int sm[256];
    int t = threadIdx.x;
    int v = (t < n) ? in[t] : 0;
    sm[t] = v;
    __syncthreads();
    for (int o = 1; o < 256; o <<= 1) {
        int a = (t >= o) ? sm[t - o] : 0;
        __syncthreads();
        sm[t] += a;
        __syncthreads();
    }
    if (t < n) out[t] = sm[t] - v;   // exclusive
}

__global__ __launch_bounds__(256) void k_scan3(const int* __restrict__ deg,
                                               const int* __restrict__ boff,
                                               int* __restrict__ rowptr,
                                               int* __restrict__ cursor) {
    __shared__ int sm[256];
    int t = threadIdx.x;
    int idx = blockIdx.x * 256 + t;
    int v = (idx < NN) ? deg[idx] : 0;
    sm[t] = v;
    __syncthreads();
    for (int o = 1; o < 256; o <<= 1) {
        int a = (t >= o) ? sm[t - o] : 0;
        __syncthreads();
        sm[t] += a;
        __syncthreads();
    }
    int incl = sm[t] + boff[blockIdx.x];
    if (idx < NN) { rowptr[idx + 1] = incl; cursor[idx] = incl - v; }
    if (idx == 0) rowptr[0] = 0;
}

__global__ __launch_bounds__(256) void k_scatter(const int* __restrict__ src,
                                                 const int* __restrict__ dst,
                                                 int* __restrict__ cursor,
                                                 int* __restrict__ csrc) {
    int e = blockIdx.x * 256 + threadIdx.x;
    if (e < EE) {
        int d = dst[e];
        int pos = atomicAdd(&cursor[d], 1);
        csrc[pos] = src[e];
    }
}

// --- degree-sorted node permutation, LDS-aggregated counting sort ---
// Per-block private histogram in LDS (atomics on ~40 hot buckets among 256
// threads), then ONE global atomic per (block, nonzero bucket) — avoids the
// 50k-atomics-on-40-addresses contention that cost 147us in the naive version.
__global__ __launch_bounds__(256) void k_dcount(const int* __restrict__ deg, int* __restrict__ dcnt) {
    __shared__ int h[256];
    int t = threadIdx.x;
    h[t] = 0;
    __syncthreads();
    int n = blockIdx.x * 256 + t;
    if (n < NN) atomicAdd(&h[min(deg[n], 255)], 1);
    __syncthreads();
    if (h[t]) atomicAdd(&dcnt[t], h[t]);
}

__global__ __launch_bounds__(256) void k_dplace(const int* __restrict__ deg,
                                                int* __restrict__ doff,
                                                int* __restrict__ perm) {
    __shared__ int h[256];
    __shared__ int base[256];
    int t = threadIdx.x;
    h[t] = 0;
    __syncthreads();
    int n = blockIdx.x * 256 + t;
    int b = 0, r = 0;
    if (n < NN) {
        b = min(deg[n], 255);
        r = atomicAdd(&h[b], 1);       // local rank within (block, bucket)
    }
    __syncthreads();
    if (h[t]) base[t] = atomicAdd(&doff[t], h[t]);   // reserve block span
    __syncthreads();
    if (n < NN) perm[base[b] + r] = n;
}

// ---------------------------------------------------------------------------
// Weight conversion: W [128 x FOUT] fp32 -> bf16 hi/lo in MFMA-fragment order:
// element (col = t*16+m, k = c*32+quad*8+j) at (((t*4+c)*4+quad)*16+m)*8+j.
// ---------------------------------------------------------------------------
struct WPack {
    const float* W[8];
    ushort* Th[8];
    ushort* Tl[8];
    int fout[8];
};

__global__ __launch_bounds__(256) void k_conv_w(WPack p) {
    int wi = blockIdx.y;
    int fout = p.fout[wi];
    int total = 128 * fout;
    int i = blockIdx.x * 256 + threadIdx.x;
    if (i >= total) return;
    int k = i / fout;
    int n = i - k * fout;
    float f = p.W[wi][i];
    ushort h = f2bf(f);
    float lo = f - bf2f(h);
    int t = n >> 4, m = n & 15, c = k >> 5, quad = (k >> 3) & 3, j = k & 7;
    int flat = ((((t * 4 + c) * 4 + quad) * 16 + m) << 3) + j;
    p.Th[wi][flat] = h;
    p.Tl[wi][flat] = f2bf(lo);
}

// ---------------------------------------------------------------------------
// Split-bf16 MFMA GEMM with LDS-staged B: O_w = X @ W_w (+ B_w), K=128.
// 4 waves/block, each wave computes a 32-row (2x16 strip) x FOUT slab.
// Per w: the whole fragment-packed weight matrix (hi+lo, <=64 KB) is staged
// into LDS cooperatively, then fragments come from ds_read_b128.
// CVT=true: A read from fp32 X and split to bf16 hi/lo on the fly (layer 0).
// ---------------------------------------------------------------------------
template <int FOUT, int NW, bool CVT>
__global__ __launch_bounds__(256) void k_gemm_mfma(
    const float* __restrict__ Xf,
    const ushort* __restrict__ Xh, const ushort* __restrict__ Xl,
    const ushort* __restrict__ T0h, const ushort* __restrict__ T0l, const float* __restrict__ B0,
    const ushort* __restrict__ T1h, const ushort* __restrict__ T1l, const float* __restrict__ B1,
    const ushort* __restrict__ T2h, const ushort* __restrict__ T2l,
    float* __restrict__ O0, float* __restrict__ O1, float* __restrict__ O2)
{
    __shared__ ushort Bsh[128 * FOUT];
    __shared__ ushort Bsl[128 * FOUT];

    const int lane = threadIdx.x & 63;
    const int wid  = threadIdx.x >> 6;
    const int m    = lane & 15;
    const int quad = lane >> 4;
    const int row0 = blockIdx.x * 128 + wid * 32;

    v8s ah[2][4], al[2][4];
    #pragma unroll
    for (int s = 0; s < 2; ++s) {
        int arow = row0 + s * 16 + m;
        if (arow > NN - 1) arow = NN - 1;
        #pragma unroll
        for (int c = 0; c < 4; ++c) {
            size_t off = (size_t)arow * 128 + c * 32 + quad * 8;
            if constexpr (CVT) {
                float4 f0 = *(const float4*)(Xf + off);
                float4 f1 = *(const float4*)(Xf + off + 4);
                const float fe[8] = {f0.x, f0.y, f0.z, f0.w, f1.x, f1.y, f1.z, f1.w};
                #pragma unroll
                for (int e = 0; e < 8; ++e) {
                    ushort h = f2bf(fe[e]);
                    float lo = fe[e] - bf2f(h);
                    ah[s][c][e] = (short)h;
                    al[s][c][e] = (short)(__float_as_uint(lo) >> 16);  // truncate lo
                }
            } else {
                ah[s][c] = *(const v8s*)(Xh + off);
                al[s][c] = *(const v8s*)(Xl + off);
            }
        }
    }

    const ushort* Th[3] = {T0h, T1h, T2h};
    const ushort* Tl[3] = {T0l, T1l, T2l};
    const float*  Bs[3] = {B0, B1, nullptr};
    float*        Os[3] = {O0, O1, O2};

    #pragma unroll
    for (int w = 0; w < NW; ++w) {
        const ushort* th = Th[w];
        const ushort* tl = Tl[w];
        if (w > 0) __syncthreads();   // previous tile's reads done
        constexpr int CHUNKS = (128 * FOUT) / 8;
        for (int idx = threadIdx.x; idx < CHUNKS; idx += 256) {
            ((uint4*)Bsh)[idx] = ((const uint4*)th)[idx];
            ((uint4*)Bsl)[idx] = ((const uint4*)tl)[idx];
        }
        __syncthreads();

        const float* bias = Bs[w];
        float* O = Os[w];
        #pragma unroll
        for (int t = 0; t < FOUT / 16; ++t) {
            v4f acc[2] = {{0.f,0.f,0.f,0.f},{0.f,0.f,0.f,0.f}};
            #pragma unroll
            for (int c = 0; c < 4; ++c) {
                int boff = t * 2048 + (c * 4 + quad) * 128 + m * 8;
                v8s bh = *(const v8s*)&Bsh[boff];
                v8s bl = *(const v8s*)&Bsl[boff];
                acc[0] = __builtin_amdgcn_mfma_f32_16x16x32_bf16(al[0][c], bh, acc[0], 0, 0, 0);
                acc[0] = __builtin_amdgcn_mfma_f32_16x16x32_bf16(ah[0][c], bl, acc[0], 0, 0, 0);
                acc[0] = __builtin_amdgcn_mfma_f32_16x16x32_bf16(ah[0][c], bh, acc[0], 0, 0, 0);
                acc[1] = __builtin_amdgcn_mfma_f32_16x16x32_bf16(al[1][c], bh, acc[1], 0, 0, 0);
                acc[1] = __builtin_amdgcn_mfma_f32_16x16x32_bf16(ah[1][c], bl, acc[1], 0, 0, 0);
                acc[1] = __builtin_amdgcn_mfma_f32_16x16x32_bf16(ah[1][c], bh, acc[1], 0, 0, 0);
            }
            const int col = t * 16 + m;
            float badd = bias ? bias[col] : 0.f;
            #pragma unroll
            for (int s = 0; s < 2; ++s) {
                #pragma unroll
                for (int j = 0; j < 4; ++j) {
                    int r = row0 + s * 16 + quad * 4 + j;
                    if (r < NN) O[(size_t)r * FOUT + col] = acc[s][j] + badd;
                }
            }
        }
    }
}

// ---------------------------------------------------------------------------
// Aggregation layers 0/1: one wave per (degree-sorted) node, 8 edges per
// main-loop iteration. Lane l: half = l>>5 selects edge of each pair; j = l&31
// owns channels 4j..4j+3. Head = j>>3 -> logit reduce = sum8 (3 DPP).
// ---------------------------------------------------------------------------
__global__ __launch_bounds__(256) void k_agg01(const float4* __restrict__ XL4,
                                               const float4* __restrict__ XR4,
                                               const float4* __restrict__ RES4,
                                               const float* __restrict__ att,
                                               const float* __restrict__ bias,
                                               const int* __restrict__ rowptr,
                                               const int* __restrict__ csrc,
                                               const int* __restrict__ perm,
                                               ushort* __restrict__ Hh,
                                               ushort* __restrict__ Hl) {
    const int lane = threadIdx.x & 63;
    const int wid = threadIdx.x >> 6;
    const int idx = blockIdx.x * 4 + wid;
    if (idx >= NN) return;
    const int n = perm[idx];
    const int beg = rowptr[n];
    const int end = rowptr[n + 1];
    const int half = lane >> 5;
    const uint j = lane & 31;

    const float4 xr = XR4[(uint)n * 32u + j];
    const float4 at = ((const float4*)att)[j];
    float4 s = {0.f, 0.f, 0.f, 0.f};
    float d = 0.f;
    const int e1 = end - 1;

    for (int i = beg; i < end; i += 8) {
        int i0 = i + half;
        int i1 = i + 2 + half;
        int i2 = i + 4 + half;
        int i3 = i + 6 + half;
        uint s0 = (uint)csrc[min(i0, e1)];
        uint s1 = (uint)csrc[min(i1, e1)];
        uint s2 = (uint)csrc[min(i2, e1)];
        uint s3 = (uint)csrc[min(i3, e1)];
        float4 v0 = XL4[s0 * 32u + j];
        float4 v1 = XL4[s1 * 32u + j];
        float4 v2 = XL4[s2 * 32u + j];
        float4 v3 = XL4[s3 * 32u + j];
        #pragma unroll
        for (int u = 0; u < 4; ++u) {
            float4 v = (u == 0) ? v0 : (u == 1) ? v1 : (u == 2) ? v2 : v3;
            int ii = (u == 0) ? i0 : (u == 1) ? i1 : (u == 2) ? i2 : i3;
            float t0 = lrelu(v.x + xr.x) * at.x;
            t0 = fmaf(lrelu(v.y + xr.y), at.y, t0);
            t0 = fmaf(lrelu(v.z + xr.z), at.z, t0);
            t0 = fmaf(lrelu(v.w + xr.w), at.w, t0);
            float p = expclamp(sum8(t0));
            if (ii >= end) p = 0.f;
            d += p;
            s.x = fmaf(p, v.x, s.x); s.y = fmaf(p, v.y, s.y);
            s.z = fmaf(p, v.z, s.z); s.w = fmaf(p, v.w, s.w);
        }
    }

    // combine the two edge-halves
    d   += __shfl_xor(d, 32);
    s.x += __shfl_xor(s.x, 32);
    s.y += __shfl_xor(s.y, 32);
    s.z += __shfl_xor(s.z, 32);
    s.w += __shfl_xor(s.w, 32);

    if (half == 0) {
        float inv = (d > 0.f) ? 1.f / d : 0.f;
        float4 rv = RES4[(uint)n * 32u + j];
        float4 bv = ((const float4*)bias)[j];
        float o0 = fmaf(s.x, inv, rv.x + bv.x);
        float o1 = fmaf(s.y, inv, rv.y + bv.y);
        float o2 = fmaf(s.z, inv, rv.z + bv.z);
        float o3 = fmaf(s.w, inv, rv.w + bv.w);
        o0 = o0 > 0.f ? o0 : __expf(o0) - 1.f;   // ELU
        o1 = o1 > 0.f ? o1 : __expf(o1) - 1.f;
        o2 = o2 > 0.f ? o2 : __expf(o2) - 1.f;
        o3 = o3 > 0.f ? o3 : __expf(o3) - 1.f;
        ushort4 h, l;
        h.x = f2bf(o0); l.x = f2bf(o0 - bf2f(h.x));
        h.y = f2bf(o1); l.y = f2bf(o1 - bf2f(h.y));
        h.z = f2bf(o2); l.z = f2bf(o2 - bf2f(h.z));
        h.w = f2bf(o3); l.w = f2bf(o3 - bf2f(h.w));
        *(ushort4*)(Hh + (uint)n * 128u + 4u * j) = h;
        *(ushort4*)(Hl + (uint)n * 128u + 4u * j) = l;
    }
}

// ---------------------------------------------------------------------------
// Aggregation layer 2: F=64, H=1, degree-sorted. 8 edges per iteration
// (2 masked quad-passes). Quarter q = l>>4 selects edge; jj = l&15 owns
// channels 4jj..4jj+3. reduce16 = 4 DPP.
// ---------------------------------------------------------------------------
__global__ __launch_bounds__(256) void k_agg2(const float4* __restrict__ XL4,
                                              const float4* __restrict__ XR4,
                                              const float* __restrict__ att,
                                              const float* __restrict__ bias,
                                              const int* __restrict__ rowptr,
                                              const int* __restrict__ csrc,
                                              const int* __restrict__ perm,
                                              float* __restrict__ OUT) {
    const int lane = threadIdx.x & 63;
    const int wid = threadIdx.x >> 6;
    const int idx = blockIdx.x * 4 + wid;
    if (idx >= NN) return;
    const int n = perm[idx];
    const int beg = rowptr[n];
    const int end = rowptr[n + 1];
    const int q = lane >> 4;
    const uint jj = lane & 15;

    const float4 xr = XR4[(uint)n * 16u + jj];
    const float4 at = ((const float4*)att)[jj];
    float4 s = {0.f, 0.f, 0.f, 0.f};
    float d = 0.f;
    const int e1 = end - 1;

    for (int i = beg; i < end; i += 8) {
        int i0 = i + q;
        int i1 = i + 4 + q;
        uint s0 = (uint)csrc[min(i0, e1)];
        uint s1 = (uint)csrc[min(i1, e1)];
        float4 v0 = XL4[s0 * 16u + jj];
        float4 v1 = XL4[s1 * 16u + jj];
        #pragma unroll
        for (int u = 0; u < 2; ++u) {
            float4 v = (u == 0) ? v0 : v1;
            int ii = (u == 0) ? i0 : i1;
            float t0 = lrelu(v.x + xr.x) * at.x;
            t0 = fmaf(lrelu(v.y + xr.y), at.y, t0);
            t0 = fmaf(lrelu(v.z + xr.z), at.z, t0);
            t0 = fmaf(lrelu(v.w + xr.w), at.w, t0);
            float p = expclamp(sum16(t0));
            if (ii >= end) p = 0.f;
            d += p;
            s.x = fmaf(p, v.x, s.x); s.y = fmaf(p, v.y, s.y);
            s.z = fmaf(p, v.z, s.z); s.w = fmaf(p, v.w, s.w);
        }
    }

    // combine the four quarters
    d   += __shfl_xor(d, 16);   d   += __shfl_xor(d, 32);
    s.x += __shfl_xor(s.x, 16); s.x += __shfl_xor(s.x, 32);
    s.y += __shfl_xor(s.y, 16); s.y += __shfl_xor(s.y, 32);
    s.z += __shfl_xor(s.z, 16); s.z += __shfl_xor(s.z, 32);
    s.w += __shfl_xor(s.w, 16); s.w += __shfl_xor(s.w, 32);

    if (lane < 16) {
        float inv = (d > 0.f) ? 1.f / d : 0.f;
        float4 bv = ((const float4*)bias)[jj];
        float4 o;
        o.x = fmaf(s.x, inv, bv.x);
        o.y = fmaf(s.y, inv, bv.y);
        o.z = fmaf(s.z, inv, bv.z);
        o.w = fmaf(s.w, inv, bv.w);
        *(float4*)(OUT + (uint)n * 64u + 4u * jj) = o;
    }
}

// ---------------------------------------------------------------------------
extern "C" void kernel_launch(void* const* d_in, const int* in_sizes, int n_in,
                              void* d_out, int out_size, void* d_ws, size_t ws_size,
                              hipStream_t stream) {
    const float* x    = (const float*)d_in[0];
    const int*   ei   = (const int*)d_in[1];
    const int*   esrc = ei;
    const int*   edst = ei + EE;

    const float* Wl0 = (const float*)d_in[2];
    const float* bl0 = (const float*)d_in[3];
    const float* Wr0 = (const float*)d_in[4];
    const float* br0 = (const float*)d_in[5];
    const float* at0 = (const float*)d_in[6];
    const float* b0  = (const float*)d_in[7];
    const float* rs0 = (const float*)d_in[8];
    const float* Wl1 = (const float*)d_in[9];
    const float* bl1 = (const float*)d_in[10];
    const float* Wr1 = (const float*)d_in[11];
    const float* br1 = (const float*)d_in[12];
    const float* at1 = (const float*)d_in[13];
    const float* b1  = (const float*)d_in[14];
    const float* rs1 = (const float*)d_in[15];
    const float* Wl2 = (const float*)d_in[16];
    const float* bl2 = (const float*)d_in[17];
    const float* Wr2 = (const float*)d_in[18];
    const float* br2 = (const float*)d_in[19];
    const float* at2 = (const float*)d_in[20];
    const float* b2  = (const float*)d_in[21];

    float* out = (float*)d_out;

    // --- workspace layout ---
    float* XL  = (float*)d_ws;                 // [NN*128] fp32 row-major
    float* XR  = XL + (size_t)NN * 128;
    float* RES = XR + (size_t)NN * 128;
    ushort* Xh = (ushort*)(RES + (size_t)NN * 128);   // [NN*128] bf16-hi (H)
    ushort* Xl_ = Xh + (size_t)NN * 128;              // [NN*128] bf16-lo (H)
    ushort* Wth = Xl_ + (size_t)NN * 128;
    const int wsz[8] = {16384, 16384, 16384, 16384, 16384, 16384, 8192, 8192};
    ushort* th[8]; ushort* tl[8];
    {
        ushort* p = Wth;
        for (int i = 0; i < 8; ++i) { th[i] = p; p += wsz[i]; }
        for (int i = 0; i < 8; ++i) { tl[i] = p; p += wsz[i]; }
    }
    int* deg    = (int*)(Wth + 2 * (6 * 16384 + 2 * 8192));
    int* dcnt   = deg + NN;                    // 256  (memset together with deg)
    int* rowptr = dcnt + 256;                  // NN+1
    int* cursor = rowptr + (NN + 1);
    int* csrc   = cursor + NN;                 // EE
    int* bsum   = csrc + EE;                   // NB
    int* boff   = bsum + NB;                   // NB
    int* doff   = boff + NB;                   // 256
    int* perm   = doff + 256;                  // NN

    // --- CSR build + degree sort (graph identical across layers) ---
    hipMemsetAsync(deg, 0, (NN + 256) * sizeof(int), stream);   // deg + dcnt
    k_hist<<<(EE + 255) / 256, 256, 0, stream>>>(edst, deg);
    k_scan1<<<NB, 256, 0, stream>>>(deg, bsum);
    k_scan256<<<1, 256, 0, stream>>>(bsum, boff, NB);
    k_scan3<<<NB, 256, 0, stream>>>(deg, boff, rowptr, cursor);
    k_scatter<<<(EE + 255) / 256, 256, 0, stream>>>(esrc, edst, cursor, csrc);
    k_dcount<<<(NN + 255) / 256, 256, 0, stream>>>(deg, dcnt);
    k_scan256<<<1, 256, 0, stream>>>(dcnt, doff, 256);
    k_dplace<<<(NN + 255) / 256, 256, 0, stream>>>(deg, doff, perm);

    // --- weight conversion ---
    WPack wp;
    const float* Ws[8] = {Wl0, Wr0, rs0, Wl1, Wr1, rs1, Wl2, Wr2};
    const int fouts[8] = {128, 128, 128, 128, 128, 128, 64, 64};
    for (int i = 0; i < 8; ++i) { wp.W[i] = Ws[i]; wp.Th[i] = th[i]; wp.Tl[i] = tl[i]; wp.fout[i] = fouts[i]; }
    k_conv_w<<<dim3(64, 8), 256, 0, stream>>>(wp);

    const int gemm_grid = (NN + 127) / 128;
    const int agg_grid  = (NN + 3) / 4;

    // --- Layer 0 (A from fp32 x, split on the fly) ---
    k_gemm_mfma<128, 3, true><<<gemm_grid, 256, 0, stream>>>(x, nullptr, nullptr,
        th[0], tl[0], bl0, th[1], tl[1], br0, th[2], tl[2], XL, XR, RES);
    k_agg01<<<agg_grid, 256, 0, stream>>>((const float4*)XL, (const float4*)XR, (const float4*)RES,
        at0, b0, rowptr, csrc, perm, Xh, Xl_);

    // --- Layer 1 ---
    k_gemm_mfma<128, 3, false><<<gemm_grid, 256, 0, stream>>>(nullptr, Xh, Xl_,
        th[3], tl[3], bl1, th[4], tl[4], br1, th[5], tl[5], XL, XR, RES);
    k_agg01<<<agg_grid, 256, 0, stream>>>((const float4*)XL, (const float4*)XR, (const float4*)RES,
        at1, b1, rowptr, csrc, perm, Xh, Xl_);

    // --- Layer 2 (heads=1, C=64, no residual, no ELU) ---
    k_gemm_mfma<64, 2, false><<<gemm_grid, 256, 0, stream>>>(nullptr, Xh, Xl_,
        th[6], tl[6], bl2, th[7], tl[7], br2, nullptr, nullptr, XL, XR, nullptr);
    k_agg2<<<agg_grid, 256, 0, stream>>>((const float4*)XL, (const float4*)XR, at2, b2, rowptr, csrc, perm, out);
}